// Round 11
// baseline (1779.175 us; speedup 1.0000x reference)
//
#include <hip/hip_runtime.h>
#include <hip/hip_bf16.h>
#include <math.h>

#define N 8192
#define BATCH 2
#define NROWS (BATCH*N)

typedef float v2f __attribute__((ext_vector_type(2)));

static __device__ __forceinline__ float fsubr(float a, float b){ return __fadd_rn(a, -b); }
static __device__ __forceinline__ unsigned okey(float f){
  unsigned u = __float_as_uint(f);
  return (u & 0x80000000u) ? ~u : (u | 0x80000000u);
}

// ---------------- aux: transpose xyz + |p|^2 + masked-coord float4 image (pre-mask copy)
__global__ void aux_kernel(const float* __restrict__ xyz, float* __restrict__ xs, float* __restrict__ ys,
                           float* __restrict__ zs, float* __restrict__ sq, float4* __restrict__ mxyz){
  int i = blockIdx.x*256 + threadIdx.x;
  if (i < NROWS){
    float x = xyz[i*3+0], y = xyz[i*3+1], z = xyz[i*3+2];
    xs[i]=x; ys[i]=y; zs[i]=z;
    sq[i] = __fadd_rn(__fadd_rn(__fmul_rn(x,x),__fmul_rn(y,y)),__fmul_rn(z,z));
    mxyz[i] = make_float4(x, y, z, 0.0f);
  }
}

// ---------------- far_val = max(xyz) + 1.0f
__global__ void farval_kernel(const float* __restrict__ xyz, float* __restrict__ farval){
  __shared__ float lm[4];
  float m = -1e30f;
  for (int i = threadIdx.x; i < NROWS*3; i += 256) m = fmaxf(m, xyz[i]);
  for (int off = 32; off; off >>= 1) m = fmaxf(m, __shfl_down(m, off));
  if ((threadIdx.x & 63) == 0) lm[threadIdx.x >> 6] = m;
  __syncthreads();
  if (threadIdx.x == 0){
    float r = fmaxf(fmaxf(lm[0],lm[1]), fmaxf(lm[2],lm[3]));
    farval[0] = __fadd_rn(r, 1.0f);
  }
}

// ---------------- Q = xyz @ w1[:3] + feat @ w1[3:]  (per global row, 128 cols)
__global__ __launch_bounds__(128) void q_kernel(const float* __restrict__ xyz, const float* __restrict__ feat,
                                                const float* __restrict__ w1, float* __restrict__ Q){
  __shared__ float sx[16][3];
  __shared__ float sf[16][64];
  const int t = threadIdx.x;
  const int row0 = blockIdx.x * 16;
  for (int j = t; j < 1024; j += 128) sf[j>>6][j&63] = feat[(size_t)row0*64 + j];
  if (t < 48) sx[t/3][t%3] = xyz[(size_t)row0*3 + t];
  __syncthreads();
  float acc[16];
  #pragma unroll
  for (int r = 0; r < 16; ++r) acc[r] = 0.0f;
  for (int c = 0; c < 3; ++c){
    float wv = w1[c*128 + t];
    #pragma unroll
    for (int r = 0; r < 16; ++r) acc[r] = fmaf(sx[r][c], wv, acc[r]);
  }
  for (int c = 0; c < 64; ++c){
    float wv = w1[(3+c)*128 + t];
    #pragma unroll
    for (int r = 0; r < 16; ++r) acc[r] = fmaf(sf[r][c], wv, acc[r]);
  }
  #pragma unroll
  for (int r = 0; r < 16; ++r) Q[(size_t)(row0+r)*128 + t] = acc[r];
}

// ---------------- KNN: per row, exact 65 smallest (d2, idx), drop rank0 (self), store 64 cand
#define BINBASE 0xBA00
__global__ __launch_bounds__(512) void knn_kernel(const float* __restrict__ xs, const float* __restrict__ ys,
                                                  const float* __restrict__ zs, const float* __restrict__ sq,
                                                  int* __restrict__ cand){
#pragma clang fp contract(off)
  __shared__ unsigned fk[N];
  __shared__ unsigned hist[2048];
  __shared__ unsigned long long win[1024];
  __shared__ int scal[8];
  const int t = threadIdx.x;
  const int base_row = blockIdx.x * 32;           // 512 blocks x 32 rows
  const int b = base_row >> 13;
  const int n0 = base_row & (N-1);
  const int pbase = b * N;
  v2f px[8], py[8], pz[8], ps[8];
  #pragma unroll
  for (int k = 0; k < 8; ++k){
    int i0 = t + (2*k)*512, i1 = t + (2*k+1)*512;
    px[k].x = xs[pbase+i0]; px[k].y = xs[pbase+i1];
    py[k].x = ys[pbase+i0]; py[k].y = ys[pbase+i1];
    pz[k].x = zs[pbase+i0]; pz[k].y = zs[pbase+i1];
    ps[k].x = sq[pbase+i0]; ps[k].y = sq[pbase+i1];
  }
  for (int r = 0; r < 32; ++r){
    const int n = n0 + r;
    const float qx = xs[pbase+n], qy = ys[pbase+n], qz = zs[pbase+n], qs = sq[pbase+n];
    #pragma unroll
    for (int j = 0; j < 4; ++j) hist[t + j*512] = 0;
    __syncthreads();
    #pragma unroll
    for (int k = 0; k < 8; ++k){
      v2f dot = px[k]*qx + py[k]*qy + pz[k]*qz;       // ((mul+mul)+mul), rn, packable
      v2f dd  = (qs + ps[k]) - 2.0f*dot;              // 2*dot exact; one rounding on sub
      unsigned u0 = okey(dd.x), u1 = okey(dd.y);
      fk[t + (2*k)*512] = u0;
      fk[t + (2*k+1)*512] = u1;
      int bin0 = (int)(u0 >> 16) - BINBASE; bin0 = bin0 < 0 ? 0 : (bin0 > 2047 ? 2047 : bin0);
      int bin1 = (int)(u1 >> 16) - BINBASE; bin1 = bin1 < 0 ? 0 : (bin1 > 2047 ? 2047 : bin1);
      atomicAdd(&hist[bin0], 1u);
      atomicAdd(&hist[bin1], 1u);
    }
    __syncthreads();
    if (t < 64){
      unsigned s = 0;
      for (int k2 = 0; k2 < 32; ++k2) s += hist[t*32 + ((k2 + t) & 31)];   // rotated: conflict-free
      unsigned p = s;
      for (int off = 1; off < 64; off <<= 1){ unsigned v = (unsigned)__shfl_up((int)p, off); if (t >= off) p += v; }
      int excl = (int)(p - s);
      if (excl < 65 && (int)p >= 65){ scal[0] = t; scal[1] = excl; }
    }
    __syncthreads();
    {
      int g = scal[0];
      if (t < 32){
        unsigned s = hist[g*32 + t];
        unsigned p = s;
        for (int off = 1; off < 32; off <<= 1){ unsigned v = (unsigned)__shfl_up((int)p, off); if (t >= off) p += v; }
        int before = scal[1] + (int)(p - s);
        if (before < 65 && scal[1] + (int)p >= 65) scal[2] = g*32 + t;
      }
    }
    if (t == 0) scal[3] = 0;
    __syncthreads();
    int B1 = scal[2];
    unsigned limit = (B1 >= 2047) ? 0xFFFFFFFFu : ((unsigned)(BINBASE + B1 + 1) << 16);
    #pragma unroll
    for (int j = 0; j < 16; ++j){
      int i = t + j*512;
      unsigned u = fk[i];
      if (u < limit){
        int p = atomicAdd(&scal[3], 1);
        if (p < 1024) win[p] = ((unsigned long long)u << 32) | (unsigned)i;
      }
    }
    __syncthreads();
    int m = scal[3]; if (m > 1024) m = 1024;
    for (int e = t; e < m; e += 512){
      unsigned long long me = win[e];
      int rk = 0;
      for (int j2 = 0; j2 < m; ++j2) rk += (win[j2] < me) ? 1 : 0;
      if (rk >= 1 && rk < 65) cand[(size_t)(pbase + n)*64 + (rk-1)] = (int)(me & 0xFFFFFFFFull);
    }
    __syncthreads();
  }
}

// ---------------- scores + top16 + covariance/eigen curvature + feat_var  (one wave per row)
__global__ __launch_bounds__(256) void score_kernel(const float* __restrict__ xyz, const float* __restrict__ feat,
                                                    const float* __restrict__ Q, const float* __restrict__ b1,
                                                    const float* __restrict__ w2, const float* __restrict__ b2,
                                                    const int* __restrict__ cand,
                                                    float* __restrict__ curv, float* __restrict__ fv){
  __shared__ float4 sb14[32], sw24[32];
  __shared__ int ssel[4][16];
  __shared__ float sdx[4][16], sdy[4][16], sdz[4][16], snrm[4][16];
  const int t = threadIdx.x;
  if (t < 32) sb14[t] = ((const float4*)b1)[t];
  else if (t < 64) sw24[t-32] = ((const float4*)w2)[t-32];
  __syncthreads();
  const int w = t >> 6, lane = t & 63;
  const int row = blockIdx.x*4 + w;               // global row
  const int b = row >> 13;
  const int pbase = b * N;
  const int n = row & (N-1);
  const int ck = cand[(size_t)row*64 + lane];
  const float4* Qn4 = (const float4*)(Q + (size_t)row * 128);
  const float4* Qc4 = (const float4*)(Q + (size_t)(pbase + ck) * 128);
  const float ks = 0.70710678118654752440f;
  float acc = 0.0f;
  for (int c = 0; c < 32; ++c){
    float4 qc = Qc4[c], qn = Qn4[c], bb = sb14[c], ww = sw24[c];
    float p0 = (qc.x - qn.x) + bb.x;
    float g0 = 0.5f * p0 * (1.0f + erff(p0 * ks));
    acc += g0 * ww.x;
    float p1 = (qc.y - qn.y) + bb.y;
    float g1 = 0.5f * p1 * (1.0f + erff(p1 * ks));
    acc += g1 * ww.y;
    float p2 = (qc.z - qn.z) + bb.z;
    float g2 = 0.5f * p2 * (1.0f + erff(p2 * ks));
    acc += g2 * ww.z;
    float p3 = (qc.w - qn.w) + bb.w;
    float g3 = 0.5f * p3 * (1.0f + erff(p3 * ks));
    acc += g3 * ww.w;
  }
  float score = acc + b2[0];
  unsigned key = okey(score);
  int rk = 0;
  for (int j = 0; j < 64; ++j){
    unsigned kj = (unsigned)__shfl((int)key, j);
    rk += (kj > key || (kj == key && j < lane)) ? 1 : 0;
  }
  float cx = xyz[(size_t)(pbase+ck)*3+0], cy = xyz[(size_t)(pbase+ck)*3+1], cz = xyz[(size_t)(pbase+ck)*3+2];
  float qxv = xyz[(size_t)(pbase+n)*3+0], qyv = xyz[(size_t)(pbase+n)*3+1], qzv = xyz[(size_t)(pbase+n)*3+2];
  if (rk < 16){
    ssel[w][rk] = ck;
    sdx[w][rk] = fsubr(cx, qxv);
    sdy[w][rk] = fsubr(cy, qyv);
    sdz[w][rk] = fsubr(cz, qzv);
  }
  __syncthreads();
  if (lane < 16){
    int si = ssel[w][lane];
    const float4* fc4 = (const float4*)(feat + (size_t)(pbase+si)*64);
    const float4* fn4 = (const float4*)(feat + (size_t)(pbase+n)*64);
    double s = 0.0;
    for (int c = 0; c < 16; ++c){
      float4 a = fc4[c], bq = fn4[c];
      float d0 = fsubr(a.x, bq.x); s += (double)d0 * (double)d0;
      float d1 = fsubr(a.y, bq.y); s += (double)d1 * (double)d1;
      float d2 = fsubr(a.z, bq.z); s += (double)d2 * (double)d2;
      float d3 = fsubr(a.w, bq.w); s += (double)d3 * (double)d3;
    }
    snrm[w][lane] = sqrtf((float)s);
  }
  __syncthreads();
  if (lane == 0){
    double cxx=0, cxy=0, cxz=0, cyy=0, cyz=0, czz=0;
    for (int k2 = 0; k2 < 16; ++k2){
      double dx = (double)sdx[w][k2], dy = (double)sdy[w][k2], dz = (double)sdz[w][k2];
      cxx += dx*dx; cxy += dx*dy; cxz += dx*dz; cyy += dy*dy; cyz += dy*dz; czz += dz*dz;
    }
    float fxx = (float)(cxx/16.0), fxy = (float)(cxy/16.0), fxz = (float)(cxz/16.0);
    float fyy = (float)(cyy/16.0), fyz = (float)(cyz/16.0), fzz = (float)(czz/16.0);
    double a = fxx, bbv = fyy, c = fzz, d = fxy, e = fyz, f = fxz;
    double p1 = d*d + f*f + e*e;
    double e0, e1, e2v;
    if (p1 == 0.0){ e0 = a; e1 = bbv; e2v = c; }
    else {
      double q = (a + bbv + c) / 3.0;
      double aa = a - q, bq = bbv - q, cc = c - q;
      double p2 = aa*aa + bq*bq + cc*cc + 2.0*p1;
      double p = sqrt(p2 / 6.0);
      double inv = 1.0 / p;
      double bxx = aa*inv, byy = bq*inv, bzz = cc*inv, bxy = d*inv, bxz = f*inv, byz = e*inv;
      double detB = bxx*(byy*bzz - byz*byz) - bxy*(bxy*bzz - byz*bxz) + bxz*(bxy*byz - byy*bxz);
      double rr = 0.5 * detB;
      rr = fmin(1.0, fmax(-1.0, rr));
      double phi = acos(rr) / 3.0;
      e0 = q + 2.0*p*cos(phi);
      e2v = q + 2.0*p*cos(phi + 2.0943951023931953);
      e1 = 3.0*q - e0 - e2v;
    }
    double s0 = fabs(e0), s1 = fabs(e1), s2d = fabs(e2v), tt;
    if (s0 < s1){ tt=s0; s0=s1; s1=tt; }
    if (s1 < s2d){ tt=s1; s1=s2d; s2d=tt; }
    if (s0 < s1){ tt=s0; s0=s1; s1=tt; }
    float sv0 = (float)s0, sv1 = (float)s1, sv2 = (float)s2d;
    float l2f = __fmul_rn(sv0,sv0), l1f = __fmul_rn(sv1,sv1), l0f = __fmul_rn(sv2,sv2);
    float den = __fadd_rn(__fadd_rn(__fadd_rn(l0f, l1f), l2f), 1e-8f);
    curv[row] = l0f / den;
    double fs = 0.0;
    for (int k2 = 0; k2 < 16; ++k2) fs += (double)snrm[w][k2];
    fv[row] = (float)(fs / 16.0);
  }
}

// ---------------- per-batch znorm + importance
static __device__ __forceinline__ double blk_sum(double v, double* lds, int t){
  for (int off = 32; off; off >>= 1) v += __shfl_down(v, off);
  int w = t >> 6, lane = t & 63;
  if (lane == 0) lds[w] = v;
  __syncthreads();
  double r = (t < 16) ? lds[t] : 0.0;
  if (t < 64){ for (int off = 8; off; off >>= 1) r += __shfl_down(r, off); }
  if (t == 0) lds[0] = r;
  __syncthreads();
  double out = lds[0];
  __syncthreads();
  return out;
}

__global__ __launch_bounds__(1024) void stats_kernel(const float* __restrict__ curv, const float* __restrict__ fv,
                                                     float* __restrict__ imp){
  __shared__ double lds[16];
  const int t = threadIdx.x;
  const int base = blockIdx.x * N;
  double sc = 0, sf = 0;
  for (int j = 0; j < 8; ++j){ int i = t + j*1024; sc += (double)curv[base+i]; sf += (double)fv[base+i]; }
  double Sc = blk_sum(sc, lds, t);
  double Sf = blk_sum(sf, lds, t);
  double mc = Sc/8192.0, mf = Sf/8192.0;
  double vc = 0, vf = 0;
  for (int j = 0; j < 8; ++j){ int i = t + j*1024;
    double d1 = (double)curv[base+i] - mc; vc += d1*d1;
    double d2 = (double)fv[base+i]  - mf; vf += d2*d2; }
  double Vc = blk_sum(vc, lds, t);
  double Vf = blk_sum(vf, lds, t);
  float mcf = (float)mc, mff = (float)mf;
  float dc = __fadd_rn((float)sqrt(Vc/8191.0), 1e-8f);
  float df = __fadd_rn((float)sqrt(Vf/8191.0), 1e-8f);
  for (int j = 0; j < 8; ++j){ int i = t + j*1024;
    float zc = fsubr(curv[base+i], mcf) / dc;
    float zf = fsubr(fv[base+i],  mff) / df;
    imp[base+i] = __fadd_rn(zc, __fmul_rn(0.5f, zf));
  }
}

// ---------------- top-1024 importance (ordered) -> curv_idx + masked-coord scatter (far)
#define TBINBASE 0x3E00
__global__ __launch_bounds__(1024) void topk_kernel(const float* __restrict__ imp, int* __restrict__ merged,
                                                    float4* __restrict__ mxyz, const float* __restrict__ farval){
  __shared__ unsigned dk[N];
  __shared__ unsigned hist[2048];
  __shared__ unsigned long long win[2048];
  __shared__ int scal[8];
  const int t = threadIdx.x;
  const int b = blockIdx.x;
  const int base = b * N;
  #pragma unroll
  for (int j = 0; j < 2; ++j) hist[t + j*1024] = 0;
  if (t == 0) scal[3] = 0;
  __syncthreads();
  for (int j = 0; j < 8; ++j){
    int i = t + j*1024;
    unsigned u = ~okey(imp[base+i]);   // ascending = descending importance
    dk[i] = u;
    int bin = (int)(u >> 16) - TBINBASE; bin = bin < 0 ? 0 : (bin > 2047 ? 2047 : bin);
    atomicAdd(&hist[bin], 1u);
  }
  __syncthreads();
  if (t < 64){
    unsigned s = 0;
    for (int k2 = 0; k2 < 32; ++k2) s += hist[t*32 + ((k2 + t) & 31)];
    unsigned p = s;
    for (int off = 1; off < 64; off <<= 1){ unsigned v = (unsigned)__shfl_up((int)p, off); if (t >= off) p += v; }
    int excl = (int)(p - s);
    if (excl < 1024 && (int)p >= 1024){ scal[0] = t; scal[1] = excl; }
  }
  __syncthreads();
  {
    int g = scal[0];
    if (t < 32){
      unsigned s = hist[g*32 + t];
      unsigned p = s;
      for (int off = 1; off < 32; off <<= 1){ unsigned v = (unsigned)__shfl_up((int)p, off); if (t >= off) p += v; }
      int before = scal[1] + (int)(p - s);
      if (before < 1024 && scal[1] + (int)p >= 1024) scal[2] = g*32 + t;
    }
  }
  __syncthreads();
  int B1 = scal[2];
  unsigned limit = (B1 >= 2047) ? 0xFFFFFFFFu : ((unsigned)(TBINBASE + B1 + 1) << 16);
  for (int j = 0; j < 8; ++j){
    int i = t + j*1024;
    unsigned u = dk[i];
    if (u < limit){
      int p = atomicAdd(&scal[3], 1);
      if (p < 2048) win[p] = ((unsigned long long)u << 13) | (unsigned)i;
    }
  }
  __syncthreads();
  int m = scal[3]; if (m > 2048) m = 2048;
  const float far = farval[0];
  for (int e = t; e < m; e += 1024){
    unsigned long long me = win[e];
    int rk = 0;
    for (int j2 = 0; j2 < m; ++j2) rk += (win[j2] < me) ? 1 : 0;
    if (rk < 1024){
      int idx = (int)(me & 0x1FFFull);
      merged[b*2048 + rk] = idx;
      mxyz[base + idx] = make_float4(far, far, far, 0.0f);
    }
  }
}

// ---------------- FPS (bit-exact fp32 chain), 1 block per batch
// R11: 1024 thr x 8 pts/thread. Hypothesis: every prior variant reported VGPR_Count~52
// < resident state (64 floats at 16 pts/thread) => compiler held arrays in AGPRs,
// paying ~80 v_accvgpr moves/thread/iter (closes the 1750 busy-cyc arithmetic).
// 8 pts/thread = 32 floats state (+~20 working) fits arch VGPRs. LDS (128 KB) already
// caps at 1 block/CU, so 16 waves (4/SIMD) cost no occupancy and hide latency better.
// Same R6 reduce semantics: DPP64 max, lane63 -> parity slot bank, 1 barrier,
// tree-max of 16 keys, winner coords via broadcast ds_read_b128 from LDS table.
#define DPP_MAX64(CTRL) { \
    int nlo = __builtin_amdgcn_update_dpp(0, klo, (CTRL), 0xf, 0xf, true); \
    int nhi = __builtin_amdgcn_update_dpp(0, khi, (CTRL), 0xf, 0xf, true); \
    unsigned long long nk = ((unsigned long long)(unsigned)nhi << 32) | (unsigned)nlo; \
    unsigned long long ck = ((unsigned long long)(unsigned)khi << 32) | (unsigned)klo; \
    if (nk > ck){ klo = nlo; khi = nhi; } \
  }
static __device__ __forceinline__ unsigned long long u64max(unsigned long long a, unsigned long long b){
  return a > b ? a : b;
}

__global__ __launch_bounds__(1024, 1) void fps_kernel(const float4* __restrict__ mxyz, int* __restrict__ merged){
  extern __shared__ float4 stab[];            // 8192 float4 = 128 KB dynamic LDS
  __shared__ unsigned long long wkey[2][16];
  const int t = threadIdx.x;
  const int b = blockIdx.x;
  const int base = b * N;
  float px[8], py[8], pz[8], md[8];
  #pragma unroll
  for (int j = 0; j < 8; ++j){
    int i = t + j*1024;
    float4 p = mxyz[base + i];
    px[j] = p.x; py[j] = p.y; pz[j] = p.z; md[j] = 1e10f;
    stab[i] = p;
  }
  if (t == 0) merged[b*2048 + 1024] = 0;      // first fps output is index 0
  __syncthreads();
  float4 w0 = stab[0];
  float lx = w0.x, ly = w0.y, lz = w0.z;
  for (int it = 0; it < 1023; ++it){
    float bestv = -1.0f; unsigned blow = 0u;
    #pragma unroll
    for (int j = 0; j < 8; ++j){
      float dx = fsubr(px[j], lx), dy = fsubr(py[j], ly), dz = fsubr(pz[j], lz);
      float d = __fadd_rn(__fadd_rn(__fmul_rn(dx,dx), __fmul_rn(dy,dy)), __fmul_rn(dz,dz));
      float nm = fminf(md[j], d);
      md[j] = nm;
      if (nm > bestv){ bestv = nm; blow = 8191u - (unsigned)(t + (j<<10)); }  // first-j kept on tie = smallest orig idx
    }
    unsigned long long key = ((unsigned long long)__float_as_uint(bestv) << 13) | (unsigned long long)blow;
    int klo = (int)(unsigned)(key & 0xFFFFFFFFull);
    int khi = (int)(unsigned)(key >> 32);
    DPP_MAX64(0x111)   // row_shr:1
    DPP_MAX64(0x112)   // row_shr:2
    DPP_MAX64(0x114)   // row_shr:4
    DPP_MAX64(0x118)   // row_shr:8
    DPP_MAX64(0x142)   // row_bcast:15
    DPP_MAX64(0x143)   // row_bcast:31  -> lane 63 holds wave max
    if ((t & 63) == 63)
      wkey[it & 1][t >> 6] = ((unsigned long long)(unsigned)khi << 32) | (unsigned)klo;
    __syncthreads();
    const unsigned long long* wk = wkey[it & 1];
    // balanced tree max over 16 wave keys (loads independent, 4-level max tree)
    unsigned long long k = u64max(
        u64max(u64max(u64max(wk[0],wk[1]), u64max(wk[2],wk[3])),
               u64max(u64max(wk[4],wk[5]), u64max(wk[6],wk[7]))),
        u64max(u64max(u64max(wk[8],wk[9]), u64max(wk[10],wk[11])),
               u64max(u64max(wk[12],wk[13]), u64max(wk[14],wk[15]))));
    const int idx = 8191 - (int)(k & 0x1FFFull);
    if (t == 0) merged[b*2048 + 1024 + it + 1] = idx;
    float4 wv = stab[idx];                    // uniform idx -> broadcast ds_read_b128
    lx = wv.x; ly = wv.y; lz = wv.z;
  }
}

// ---------------- gather outputs: coords + merged-as-float
__global__ void finalize_kernel(const float* __restrict__ xyz, const int* __restrict__ merged,
                                float* __restrict__ out){
  int i = blockIdx.x*256 + threadIdx.x;
  if (i < BATCH*2048){
    int b = i >> 11;
    int idx = merged[i];
    out[12288 + i] = (float)idx;
    const float* p = xyz + (size_t)(b*N + idx)*3;
    out[i*3+0] = p[0]; out[i*3+1] = p[1]; out[i*3+2] = p[2];
  }
}

extern "C" void kernel_launch(void* const* d_in, const int* in_sizes, int n_in,
                              void* d_out, int out_size, void* d_ws, size_t ws_size,
                              hipStream_t stream){
  const float* xyz  = (const float*)d_in[0];
  const float* feat = (const float*)d_in[1];
  const float* w1   = (const float*)d_in[2];
  const float* b1   = (const float*)d_in[3];
  const float* w2   = (const float*)d_in[4];
  const float* b2   = (const float*)d_in[5];
  float* out = (float*)d_out;
  char* ws = (char*)d_ws;
  float*  Q      = (float*) (ws);                  // 16384*128 f32 = 8 MB
  int*    cand   = (int*)   (ws + 8388608);        // 16384*64  i32 = 4 MB
  float*  xs     = (float*) (ws + 12582912);
  float*  ysv    = (float*) (ws + 12648448);
  float*  zsv    = (float*) (ws + 12713984);
  float*  sq     = (float*) (ws + 12779520);
  float*  curv   = (float*) (ws + 12845056);
  float*  fv     = (float*) (ws + 12910592);
  float*  imp    = (float*) (ws + 12976128);
  int*    merged = (int*)   (ws + 13041664);       // 4096 i32
  float*  farval = (float*) (ws + 13058048);       // 1 f32 (+pad)
  float4* mxyz   = (float4*)(ws + 13058112);       // 16384 float4 = 256 KB (16B aligned)

  aux_kernel<<<64, 256, 0, stream>>>(xyz, xs, ysv, zsv, sq, mxyz);
  farval_kernel<<<1, 256, 0, stream>>>(xyz, farval);
  q_kernel<<<1024, 128, 0, stream>>>(xyz, feat, w1, Q);
  knn_kernel<<<512, 512, 0, stream>>>(xs, ysv, zsv, sq, cand);
  score_kernel<<<4096, 256, 0, stream>>>(xyz, feat, Q, b1, w2, b2, cand, curv, fv);
  stats_kernel<<<2, 1024, 0, stream>>>(curv, fv, imp);
  topk_kernel<<<2, 1024, 0, stream>>>(imp, merged, mxyz, farval);
  fps_kernel<<<2, 1024, 131072, stream>>>(mxyz, merged);
  finalize_kernel<<<16, 256, 0, stream>>>(xyz, merged, out);
}

// Round 12
// 1605.267 us; speedup vs baseline: 1.1083x; 1.1083x over previous
//
#include <hip/hip_runtime.h>
#include <hip/hip_bf16.h>
#include <math.h>

#define N 8192
#define BATCH 2
#define NROWS (BATCH*N)

typedef float v2f __attribute__((ext_vector_type(2)));

static __device__ __forceinline__ float fsubr(float a, float b){ return __fadd_rn(a, -b); }
static __device__ __forceinline__ unsigned okey(float f){
  unsigned u = __float_as_uint(f);
  return (u & 0x80000000u) ? ~u : (u | 0x80000000u);
}

// ---------------- aux: transpose xyz + |p|^2 + masked-coord image + global max (okey atomicMax)
__global__ void aux_kernel(const float* __restrict__ xyz, float* __restrict__ xs, float* __restrict__ ys,
                           float* __restrict__ zs, float* __restrict__ sq, float4* __restrict__ mxyz,
                           unsigned* __restrict__ farkey){
  __shared__ unsigned lm[4];
  const int t = threadIdx.x;
  int i = blockIdx.x*256 + t;
  float m = -1e30f;
  if (i < NROWS){
    float x = xyz[i*3+0], y = xyz[i*3+1], z = xyz[i*3+2];
    xs[i]=x; ys[i]=y; zs[i]=z;
    sq[i] = __fadd_rn(__fadd_rn(__fmul_rn(x,x),__fmul_rn(y,y)),__fmul_rn(z,z));
    mxyz[i] = make_float4(x, y, z, 0.0f);
    m = fmaxf(fmaxf(x, y), z);
  }
  #pragma unroll
  for (int off = 32; off; off >>= 1) m = fmaxf(m, __shfl_down(m, off));
  if ((t & 63) == 0) lm[t >> 6] = okey(m);
  __syncthreads();
  if (t == 0){
    unsigned k = lm[0];
    k = k > lm[1] ? k : lm[1];
    k = k > lm[2] ? k : lm[2];
    k = k > lm[3] ? k : lm[3];
    atomicMax(farkey, k);
  }
}

// ---------------- Q = xyz @ w1[:3] + feat @ w1[3:]  (per global row, 128 cols)
__global__ __launch_bounds__(128) void q_kernel(const float* __restrict__ xyz, const float* __restrict__ feat,
                                                const float* __restrict__ w1, float* __restrict__ Q){
  __shared__ float sx[16][3];
  __shared__ float sf[16][64];
  const int t = threadIdx.x;
  const int row0 = blockIdx.x * 16;
  for (int j = t; j < 1024; j += 128) sf[j>>6][j&63] = feat[(size_t)row0*64 + j];
  if (t < 48) sx[t/3][t%3] = xyz[(size_t)row0*3 + t];
  __syncthreads();
  float acc[16];
  #pragma unroll
  for (int r = 0; r < 16; ++r) acc[r] = 0.0f;
  for (int c = 0; c < 3; ++c){
    float wv = w1[c*128 + t];
    #pragma unroll
    for (int r = 0; r < 16; ++r) acc[r] = fmaf(sx[r][c], wv, acc[r]);
  }
  for (int c = 0; c < 64; ++c){
    float wv = w1[(3+c)*128 + t];
    #pragma unroll
    for (int r = 0; r < 16; ++r) acc[r] = fmaf(sf[r][c], wv, acc[r]);
  }
  #pragma unroll
  for (int r = 0; r < 16; ++r) Q[(size_t)(row0+r)*128 + t] = acc[r];
}

// ---------------- KNN: per row, exact 65 smallest (d2, idx), drop rank0 (self), store 64 cand
#define BINBASE 0xBA00
__global__ __launch_bounds__(512) void knn_kernel(const float* __restrict__ xs, const float* __restrict__ ys,
                                                  const float* __restrict__ zs, const float* __restrict__ sq,
                                                  int* __restrict__ cand){
#pragma clang fp contract(off)
  __shared__ unsigned fk[N];
  __shared__ unsigned hist[2048];
  __shared__ unsigned long long win[1024];
  __shared__ int scal[8];
  const int t = threadIdx.x;
  const int base_row = blockIdx.x * 32;           // 512 blocks x 32 rows
  const int b = base_row >> 13;
  const int n0 = base_row & (N-1);
  const int pbase = b * N;
  v2f px[8], py[8], pz[8], ps[8];
  #pragma unroll
  for (int k = 0; k < 8; ++k){
    int i0 = t + (2*k)*512, i1 = t + (2*k+1)*512;
    px[k].x = xs[pbase+i0]; px[k].y = xs[pbase+i1];
    py[k].x = ys[pbase+i0]; py[k].y = ys[pbase+i1];
    pz[k].x = zs[pbase+i0]; pz[k].y = zs[pbase+i1];
    ps[k].x = sq[pbase+i0]; ps[k].y = sq[pbase+i1];
  }
  for (int r = 0; r < 32; ++r){
    const int n = n0 + r;
    const float qx = xs[pbase+n], qy = ys[pbase+n], qz = zs[pbase+n], qs = sq[pbase+n];
    #pragma unroll
    for (int j = 0; j < 4; ++j) hist[t + j*512] = 0;
    __syncthreads();
    #pragma unroll
    for (int k = 0; k < 8; ++k){
      v2f dot = px[k]*qx + py[k]*qy + pz[k]*qz;       // ((mul+mul)+mul), rn, packable
      v2f dd  = (qs + ps[k]) - 2.0f*dot;              // 2*dot exact; one rounding on sub
      unsigned u0 = okey(dd.x), u1 = okey(dd.y);
      fk[t + (2*k)*512] = u0;
      fk[t + (2*k+1)*512] = u1;
      int bin0 = (int)(u0 >> 16) - BINBASE; bin0 = bin0 < 0 ? 0 : (bin0 > 2047 ? 2047 : bin0);
      int bin1 = (int)(u1 >> 16) - BINBASE; bin1 = bin1 < 0 ? 0 : (bin1 > 2047 ? 2047 : bin1);
      atomicAdd(&hist[bin0], 1u);
      atomicAdd(&hist[bin1], 1u);
    }
    __syncthreads();
    if (t < 64){
      unsigned s = 0;
      for (int k2 = 0; k2 < 32; ++k2) s += hist[t*32 + ((k2 + t) & 31)];   // rotated: conflict-free
      unsigned p = s;
      for (int off = 1; off < 64; off <<= 1){ unsigned v = (unsigned)__shfl_up((int)p, off); if (t >= off) p += v; }
      int excl = (int)(p - s);
      if (excl < 65 && (int)p >= 65){ scal[0] = t; scal[1] = excl; }
    }
    __syncthreads();
    {
      int g = scal[0];
      if (t < 32){
        unsigned s = hist[g*32 + t];
        unsigned p = s;
        for (int off = 1; off < 32; off <<= 1){ unsigned v = (unsigned)__shfl_up((int)p, off); if (t >= off) p += v; }
        int before = scal[1] + (int)(p - s);
        if (before < 65 && scal[1] + (int)p >= 65) scal[2] = g*32 + t;
      }
    }
    if (t == 0) scal[3] = 0;
    __syncthreads();
    int B1 = scal[2];
    unsigned limit = (B1 >= 2047) ? 0xFFFFFFFFu : ((unsigned)(BINBASE + B1 + 1) << 16);
    #pragma unroll
    for (int j = 0; j < 16; ++j){
      int i = t + j*512;
      unsigned u = fk[i];
      if (u < limit){
        int p = atomicAdd(&scal[3], 1);
        if (p < 1024) win[p] = ((unsigned long long)u << 32) | (unsigned)i;
      }
    }
    __syncthreads();
    int m = scal[3]; if (m > 1024) m = 1024;
    for (int e = t; e < m; e += 512){
      unsigned long long me = win[e];
      int rk = 0;
      for (int j2 = 0; j2 < m; ++j2) rk += (win[j2] < me) ? 1 : 0;
      if (rk >= 1 && rk < 65) cand[(size_t)(pbase + n)*64 + (rk-1)] = (int)(me & 0xFFFFFFFFull);
    }
    __syncthreads();
  }
}

// ---------------- scores + top16 + covariance/eigen curvature + feat_var  (one wave per row)
__global__ __launch_bounds__(256) void score_kernel(const float* __restrict__ xyz, const float* __restrict__ feat,
                                                    const float* __restrict__ Q, const float* __restrict__ b1,
                                                    const float* __restrict__ w2, const float* __restrict__ b2,
                                                    const int* __restrict__ cand,
                                                    float* __restrict__ curv, float* __restrict__ fv){
  __shared__ float4 sb14[32], sw24[32];
  __shared__ int ssel[4][16];
  __shared__ float sdx[4][16], sdy[4][16], sdz[4][16], snrm[4][16];
  const int t = threadIdx.x;
  if (t < 32) sb14[t] = ((const float4*)b1)[t];
  else if (t < 64) sw24[t-32] = ((const float4*)w2)[t-32];
  __syncthreads();
  const int w = t >> 6, lane = t & 63;
  const int row = blockIdx.x*4 + w;               // global row
  const int b = row >> 13;
  const int pbase = b * N;
  const int n = row & (N-1);
  const int ck = cand[(size_t)row*64 + lane];
  const float4* Qn4 = (const float4*)(Q + (size_t)row * 128);
  const float4* Qc4 = (const float4*)(Q + (size_t)(pbase + ck) * 128);
  const float ks = 0.70710678118654752440f;
  float acc = 0.0f;
  for (int c = 0; c < 32; ++c){
    float4 qc = Qc4[c], qn = Qn4[c], bb = sb14[c], ww = sw24[c];
    float p0 = (qc.x - qn.x) + bb.x;
    float g0 = 0.5f * p0 * (1.0f + erff(p0 * ks));
    acc += g0 * ww.x;
    float p1 = (qc.y - qn.y) + bb.y;
    float g1 = 0.5f * p1 * (1.0f + erff(p1 * ks));
    acc += g1 * ww.y;
    float p2 = (qc.z - qn.z) + bb.z;
    float g2 = 0.5f * p2 * (1.0f + erff(p2 * ks));
    acc += g2 * ww.z;
    float p3 = (qc.w - qn.w) + bb.w;
    float g3 = 0.5f * p3 * (1.0f + erff(p3 * ks));
    acc += g3 * ww.w;
  }
  float score = acc + b2[0];
  unsigned key = okey(score);
  int rk = 0;
  for (int j = 0; j < 64; ++j){
    unsigned kj = (unsigned)__shfl((int)key, j);
    rk += (kj > key || (kj == key && j < lane)) ? 1 : 0;
  }
  float cx = xyz[(size_t)(pbase+ck)*3+0], cy = xyz[(size_t)(pbase+ck)*3+1], cz = xyz[(size_t)(pbase+ck)*3+2];
  float qxv = xyz[(size_t)(pbase+n)*3+0], qyv = xyz[(size_t)(pbase+n)*3+1], qzv = xyz[(size_t)(pbase+n)*3+2];
  if (rk < 16){
    ssel[w][rk] = ck;
    sdx[w][rk] = fsubr(cx, qxv);
    sdy[w][rk] = fsubr(cy, qyv);
    sdz[w][rk] = fsubr(cz, qzv);
  }
  __syncthreads();
  if (lane < 16){
    int si = ssel[w][lane];
    const float4* fc4 = (const float4*)(feat + (size_t)(pbase+si)*64);
    const float4* fn4 = (const float4*)(feat + (size_t)(pbase+n)*64);
    double s = 0.0;
    for (int c = 0; c < 16; ++c){
      float4 a = fc4[c], bq = fn4[c];
      float d0 = fsubr(a.x, bq.x); s += (double)d0 * (double)d0;
      float d1 = fsubr(a.y, bq.y); s += (double)d1 * (double)d1;
      float d2 = fsubr(a.z, bq.z); s += (double)d2 * (double)d2;
      float d3 = fsubr(a.w, bq.w); s += (double)d3 * (double)d3;
    }
    snrm[w][lane] = sqrtf((float)s);
  }
  __syncthreads();
  if (lane == 0){
    double cxx=0, cxy=0, cxz=0, cyy=0, cyz=0, czz=0;
    for (int k2 = 0; k2 < 16; ++k2){
      double dx = (double)sdx[w][k2], dy = (double)sdy[w][k2], dz = (double)sdz[w][k2];
      cxx += dx*dx; cxy += dx*dy; cxz += dx*dz; cyy += dy*dy; cyz += dy*dz; czz += dz*dz;
    }
    float fxx = (float)(cxx/16.0), fxy = (float)(cxy/16.0), fxz = (float)(cxz/16.0);
    float fyy = (float)(cyy/16.0), fyz = (float)(cyz/16.0), fzz = (float)(czz/16.0);
    double a = fxx, bbv = fyy, c = fzz, d = fxy, e = fyz, f = fxz;
    double p1 = d*d + f*f + e*e;
    double e0, e1, e2v;
    if (p1 == 0.0){ e0 = a; e1 = bbv; e2v = c; }
    else {
      double q = (a + bbv + c) / 3.0;
      double aa = a - q, bq = bbv - q, cc = c - q;
      double p2 = aa*aa + bq*bq + cc*cc + 2.0*p1;
      double p = sqrt(p2 / 6.0);
      double inv = 1.0 / p;
      double bxx = aa*inv, byy = bq*inv, bzz = cc*inv, bxy = d*inv, bxz = f*inv, byz = e*inv;
      double detB = bxx*(byy*bzz - byz*byz) - bxy*(bxy*bzz - byz*bxz) + bxz*(bxy*byz - byy*bxz);
      double rr = 0.5 * detB;
      rr = fmin(1.0, fmax(-1.0, rr));
      double phi = acos(rr) / 3.0;
      e0 = q + 2.0*p*cos(phi);
      e2v = q + 2.0*p*cos(phi + 2.0943951023931953);
      e1 = 3.0*q - e0 - e2v;
    }
    double s0 = fabs(e0), s1 = fabs(e1), s2d = fabs(e2v), tt;
    if (s0 < s1){ tt=s0; s0=s1; s1=tt; }
    if (s1 < s2d){ tt=s1; s1=s2d; s2d=tt; }
    if (s0 < s1){ tt=s0; s0=s1; s1=tt; }
    float sv0 = (float)s0, sv1 = (float)s1, sv2 = (float)s2d;
    float l2f = __fmul_rn(sv0,sv0), l1f = __fmul_rn(sv1,sv1), l0f = __fmul_rn(sv2,sv2);
    float den = __fadd_rn(__fadd_rn(__fadd_rn(l0f, l1f), l2f), 1e-8f);
    curv[row] = l0f / den;
    double fs = 0.0;
    for (int k2 = 0; k2 < 16; ++k2) fs += (double)snrm[w][k2];
    fv[row] = (float)(fs / 16.0);
  }
}

// ---------------- merged: per-batch znorm + importance (regs) -> top-1024 + masked-coord scatter
static __device__ __forceinline__ double blk_sum(double v, double* lds, int t){
  for (int off = 32; off; off >>= 1) v += __shfl_down(v, off);
  int w = t >> 6, lane = t & 63;
  if (lane == 0) lds[w] = v;
  __syncthreads();
  double r = (t < 16) ? lds[t] : 0.0;
  if (t < 64){ for (int off = 8; off; off >>= 1) r += __shfl_down(r, off); }
  if (t == 0) lds[0] = r;
  __syncthreads();
  double out = lds[0];
  __syncthreads();
  return out;
}

#define TBINBASE 0x3E00
__global__ __launch_bounds__(1024) void stats_topk_kernel(const float* __restrict__ curv, const float* __restrict__ fv,
                                                          int* __restrict__ merged, float4* __restrict__ mxyz,
                                                          const unsigned* __restrict__ farkey){
  __shared__ unsigned dk[N];
  __shared__ unsigned hist[2048];
  __shared__ unsigned long long win[2048];
  __shared__ int scal[8];
  __shared__ double lds[16];
  const int t = threadIdx.x;
  const int b = blockIdx.x;
  const int base = b * N;
  // ---- stats phase (imp stays in registers) ----
  double sc = 0, sf = 0;
  for (int j = 0; j < 8; ++j){ int i = t + j*1024; sc += (double)curv[base+i]; sf += (double)fv[base+i]; }
  double Sc = blk_sum(sc, lds, t);
  double Sf = blk_sum(sf, lds, t);
  double mc = Sc/8192.0, mf = Sf/8192.0;
  double vc = 0, vf = 0;
  for (int j = 0; j < 8; ++j){ int i = t + j*1024;
    double d1 = (double)curv[base+i] - mc; vc += d1*d1;
    double d2 = (double)fv[base+i]  - mf; vf += d2*d2; }
  double Vc = blk_sum(vc, lds, t);
  double Vf = blk_sum(vf, lds, t);
  float mcf = (float)mc, mff = (float)mf;
  float dc = __fadd_rn((float)sqrt(Vc/8191.0), 1e-8f);
  float df = __fadd_rn((float)sqrt(Vf/8191.0), 1e-8f);
  // ---- topk phase ----
  #pragma unroll
  for (int j = 0; j < 2; ++j) hist[t + j*1024] = 0;
  if (t == 0) scal[3] = 0;
  __syncthreads();
  for (int j = 0; j < 8; ++j){
    int i = t + j*1024;
    float zc = fsubr(curv[base+i], mcf) / dc;
    float zf = fsubr(fv[base+i],  mff) / df;
    float impv = __fadd_rn(zc, __fmul_rn(0.5f, zf));
    unsigned u = ~okey(impv);          // ascending = descending importance
    dk[i] = u;
    int bin = (int)(u >> 16) - TBINBASE; bin = bin < 0 ? 0 : (bin > 2047 ? 2047 : bin);
    atomicAdd(&hist[bin], 1u);
  }
  __syncthreads();
  if (t < 64){
    unsigned s = 0;
    for (int k2 = 0; k2 < 32; ++k2) s += hist[t*32 + ((k2 + t) & 31)];
    unsigned p = s;
    for (int off = 1; off < 64; off <<= 1){ unsigned v = (unsigned)__shfl_up((int)p, off); if (t >= off) p += v; }
    int excl = (int)(p - s);
    if (excl < 1024 && (int)p >= 1024){ scal[0] = t; scal[1] = excl; }
  }
  __syncthreads();
  {
    int g = scal[0];
    if (t < 32){
      unsigned s = hist[g*32 + t];
      unsigned p = s;
      for (int off = 1; off < 32; off <<= 1){ unsigned v = (unsigned)__shfl_up((int)p, off); if (t >= off) p += v; }
      int before = scal[1] + (int)(p - s);
      if (before < 1024 && scal[1] + (int)p >= 1024) scal[2] = g*32 + t;
    }
  }
  __syncthreads();
  int B1 = scal[2];
  unsigned limit = (B1 >= 2047) ? 0xFFFFFFFFu : ((unsigned)(TBINBASE + B1 + 1) << 16);
  for (int j = 0; j < 8; ++j){
    int i = t + j*1024;
    unsigned u = dk[i];
    if (u < limit){
      int p = atomicAdd(&scal[3], 1);
      if (p < 2048) win[p] = ((unsigned long long)u << 13) | (unsigned)i;
    }
  }
  __syncthreads();
  int m = scal[3]; if (m > 2048) m = 2048;
  unsigned fk2 = *farkey;
  float rmax = (fk2 & 0x80000000u) ? __uint_as_float(fk2 & 0x7FFFFFFFu) : __uint_as_float(~fk2);
  const float far = __fadd_rn(rmax, 1.0f);
  for (int e = t; e < m; e += 1024){
    unsigned long long me = win[e];
    int rk = 0;
    for (int j2 = 0; j2 < m; ++j2) rk += (win[j2] < me) ? 1 : 0;
    if (rk < 1024){
      int idx = (int)(me & 0x1FFFull);
      merged[b*2048 + rk] = idx;
      mxyz[base + idx] = make_float4(far, far, far, 0.0f);
    }
  }
}

// ---------------- FPS (bit-exact fp32 chain), 1 block per batch — exact R6 structure (890 us)
// + finalize tail (post-loop, off the per-iteration chain): gather coords + idx-as-float.
#define DPP_MAX64(CTRL) { \
    int nlo = __builtin_amdgcn_update_dpp(0, klo, (CTRL), 0xf, 0xf, true); \
    int nhi = __builtin_amdgcn_update_dpp(0, khi, (CTRL), 0xf, 0xf, true); \
    unsigned long long nk = ((unsigned long long)(unsigned)nhi << 32) | (unsigned)nlo; \
    unsigned long long ck = ((unsigned long long)(unsigned)khi << 32) | (unsigned)klo; \
    if (nk > ck){ klo = nlo; khi = nhi; } \
  }

__global__ __launch_bounds__(512, 2) void fps_kernel(const float4* __restrict__ mxyz, int* __restrict__ merged,
                                                     const float* __restrict__ xyz, float* __restrict__ out){
  extern __shared__ float4 stab[];            // 8192 float4 = 128 KB dynamic LDS
  __shared__ unsigned long long wkey[2][8];
  const int t = threadIdx.x;
  const int b = blockIdx.x;
  const int base = b * N;
  float px[16], py[16], pz[16], md[16];
  #pragma unroll
  for (int j = 0; j < 16; ++j){
    int i = t + j*512;
    float4 p = mxyz[base + i];
    px[j] = p.x; py[j] = p.y; pz[j] = p.z; md[j] = 1e10f;
    stab[i] = p;
  }
  if (t == 0) merged[b*2048 + 1024] = 0;      // first fps output is index 0
  __syncthreads();
  float4 w0 = stab[0];
  float lx = w0.x, ly = w0.y, lz = w0.z;
  for (int it = 0; it < 1023; ++it){
    float bestv = -1.0f; unsigned blow = 0u;
    #pragma unroll
    for (int j = 0; j < 16; ++j){
      float dx = fsubr(px[j], lx), dy = fsubr(py[j], ly), dz = fsubr(pz[j], lz);
      float d = __fadd_rn(__fadd_rn(__fmul_rn(dx,dx), __fmul_rn(dy,dy)), __fmul_rn(dz,dz));
      float nm = fminf(md[j], d);
      md[j] = nm;
      if (nm > bestv){ bestv = nm; blow = 8191u - (unsigned)(t + (j<<9)); }  // first-j kept on tie = smallest orig idx
    }
    unsigned long long key = ((unsigned long long)__float_as_uint(bestv) << 13) | (unsigned long long)blow;
    int klo = (int)(unsigned)(key & 0xFFFFFFFFull);
    int khi = (int)(unsigned)(key >> 32);
    DPP_MAX64(0x111)   // row_shr:1
    DPP_MAX64(0x112)   // row_shr:2
    DPP_MAX64(0x114)   // row_shr:4
    DPP_MAX64(0x118)   // row_shr:8
    DPP_MAX64(0x142)   // row_bcast:15
    DPP_MAX64(0x143)   // row_bcast:31  -> lane 63 holds wave max
    if ((t & 63) == 63)
      wkey[it & 1][t >> 6] = ((unsigned long long)(unsigned)khi << 32) | (unsigned)klo;
    __syncthreads();
    const unsigned long long* wk = wkey[it & 1];
    unsigned long long k = wk[0];
    #pragma unroll
    for (int i2 = 1; i2 < 8; ++i2){ unsigned long long o = wk[i2]; if (o > k) k = o; }
    const int idx = 8191 - (int)(k & 0x1FFFull);
    if (t == 0) merged[b*2048 + 1024 + it + 1] = idx;
    float4 wv = stab[idx];                    // uniform idx -> broadcast ds_read_b128
    lx = wv.x; ly = wv.y; lz = wv.z;
  }
  // ---- finalize tail: this batch's 2048 outputs (coords + idx-as-float) ----
  __threadfence_block();
  __syncthreads();
  for (int e = t; e < 2048; e += 512){
    int gi = b*2048 + e;
    int idx = merged[gi];
    out[12288 + gi] = (float)idx;
    const float* p = xyz + (size_t)(base + idx)*3;
    out[gi*3+0] = p[0]; out[gi*3+1] = p[1]; out[gi*3+2] = p[2];
  }
}

extern "C" void kernel_launch(void* const* d_in, const int* in_sizes, int n_in,
                              void* d_out, int out_size, void* d_ws, size_t ws_size,
                              hipStream_t stream){
  const float* xyz  = (const float*)d_in[0];
  const float* feat = (const float*)d_in[1];
  const float* w1   = (const float*)d_in[2];
  const float* b1   = (const float*)d_in[3];
  const float* w2   = (const float*)d_in[4];
  const float* b2   = (const float*)d_in[5];
  float* out = (float*)d_out;
  char* ws = (char*)d_ws;
  float*    Q      = (float*)   (ws);                  // 16384*128 f32 = 8 MB
  int*      cand   = (int*)     (ws + 8388608);        // 16384*64  i32 = 4 MB
  float*    xs     = (float*)   (ws + 12582912);
  float*    ysv    = (float*)   (ws + 12648448);
  float*    zsv    = (float*)   (ws + 12713984);
  float*    sq     = (float*)   (ws + 12779520);
  float*    curv   = (float*)   (ws + 12845056);
  float*    fv     = (float*)   (ws + 12910592);
  int*      merged = (int*)     (ws + 13041664);       // 4096 i32
  unsigned* farkey = (unsigned*)(ws + 13058048);       // 1 u32 (okey-encoded global max)
  float4*   mxyz   = (float4*)  (ws + 13058112);       // 16384 float4 = 256 KB (16B aligned)

  hipMemsetAsync(farkey, 0, 4, stream);
  aux_kernel<<<64, 256, 0, stream>>>(xyz, xs, ysv, zsv, sq, mxyz, farkey);
  q_kernel<<<1024, 128, 0, stream>>>(xyz, feat, w1, Q);
  knn_kernel<<<512, 512, 0, stream>>>(xs, ysv, zsv, sq, cand);
  score_kernel<<<4096, 256, 0, stream>>>(xyz, feat, Q, b1, w2, b2, cand, curv, fv);
  stats_topk_kernel<<<2, 1024, 0, stream>>>(curv, fv, merged, mxyz, farkey);
  fps_kernel<<<2, 512, 131072, stream>>>(mxyz, merged, xyz, out);
}